// Round 20
// baseline (330.620 us; speedup 1.0000x reference)
//
#include <hip/hip_runtime.h>
#include <hip/hip_bf16.h>

// Problem dims
#define NB 32768
#define LL 8
#define EBD 128
#define NKK 64
#define FEAT 960
#define KDIM 1024   // LL*EBD

typedef __attribute__((ext_vector_type(8))) __bf16 bf16x8;
typedef __attribute__((ext_vector_type(4))) float f32x4;
typedef __attribute__((ext_vector_type(8))) unsigned short u16x8;

// ---------------- Kernel Q: embeddings + fc1 + hard quantize -> XQ (swizzled layout)
// [VERBATIM round-19: 2-pair fc1 + sequential quantizer, VGPR 124, 180us]
__global__ __launch_bounds__(256) void kq(const int* __restrict__ x,
    const float* __restrict__ len_emb, const float* __restrict__ ipd_emb,
    const float* __restrict__ fc1_w, const float* __restrict__ fc1_b,
    const float* __restrict__ S, const float* __restrict__ Hm,
    const float* __restrict__ T, const float* __restrict__ LUT,
    char* __restrict__ XQ)
{
    const int g = blockIdx.x;                       // 256 groups of 128 b
    const int w = threadIdx.x >> 6, lane = threadIdx.x & 63;
    const int l = blockIdx.y * 2 + (w >> 1);        // grid.y = 4 -> l in [0,8)
    const int half = w & 1;                         // which 8 chunks
    const int b0 = g * 128 + lane;
    const int p0 = b0 * 8 + l;
    const int p1 = (b0 + 64) * 8 + l;

    float e0[32], e1[32];
    {
        const float4* a0 = reinterpret_cast<const float4*>(len_emb + x[p0 * 2 + 0] * 16);
        const float4* c0 = reinterpret_cast<const float4*>(ipd_emb + x[p0 * 2 + 1] * 16);
        const float4* a1 = reinterpret_cast<const float4*>(len_emb + x[p1 * 2 + 0] * 16);
        const float4* c1 = reinterpret_cast<const float4*>(ipd_emb + x[p1 * 2 + 1] * 16);
        #pragma unroll
        for (int q = 0; q < 4; ++q) {
            float4 v = a0[q];
            e0[q * 4 + 0] = v.x; e0[q * 4 + 1] = v.y; e0[q * 4 + 2] = v.z; e0[q * 4 + 3] = v.w;
            v = c0[q];
            e0[16 + q * 4 + 0] = v.x; e0[16 + q * 4 + 1] = v.y; e0[16 + q * 4 + 2] = v.z; e0[16 + q * 4 + 3] = v.w;
            v = a1[q];
            e1[q * 4 + 0] = v.x; e1[q * 4 + 1] = v.y; e1[q * 4 + 2] = v.z; e1[q * 4 + 3] = v.w;
            v = c1[q];
            e1[16 + q * 4 + 0] = v.x; e1[16 + q * 4 + 1] = v.y; e1[16 + q * 4 + 2] = v.z; e1[16 + q * 4 + 3] = v.w;
        }
    }

    char* outbase0 = XQ + (size_t)(g * 2 + 0) * 131072 + (size_t)l * 16384 + lane * 16;
    char* outbase1 = XQ + (size_t)(g * 2 + 1) * 131072 + (size_t)l * 16384 + lane * 16;

    for (int mm = 0; mm < 8; ++mm) {
        const int m = half * 8 + mm;
        const int c = m & 3;

        float h0[8], h1[8];
        #pragma unroll
        for (int d = 0; d < 8; ++d) {
            const float* wr = fc1_w + (m * 8 + d) * 32;
            float acc0 = 0.f, acc1 = 0.f;
            #pragma unroll
            for (int j = 0; j < 32; ++j) {
                float wv = wr[j];
                acc0 += e0[j] * wv;
                acc1 += e1[j] * wv;
            }
            float bv = fc1_b[m * 8 + d];
            h0[d] = acc0 + bv;
            h1[d] = acc1 + bv;
        }

        // ---- quantize pair 0 (single-chain, verbatim r13 order) ----
        {
            float sgn[15];
            #pragma unroll
            for (int k = 0; k < 15; ++k) {
                float z = 0.f;
                #pragma unroll
                for (int d = 0; d < 8; ++d) z += h0[d] * S[(c * 8 + d) * 15 + k];
                z = z - T[c * 15 + k];
                z = z - 1e-4f;
                sgn[k] = (z > 0.f) ? 1.f : ((z < 0.f) ? -1.f : 0.f);
            }
            float best = 0.f; int jm = 0;
            #pragma unroll
            for (int j = 0; j < 16; ++j) {
                float z2 = 0.f;
                #pragma unroll
                for (int k = 0; k < 15; ++k) z2 += sgn[k] * Hm[k * 16 + j];
                if (j == 0 || z2 > best) { best = z2; jm = j; }
            }
            const float4* lr = reinterpret_cast<const float4*>(LUT + (c * 16 + jm) * 8);
            float4 l0 = lr[0], l1 = lr[1];
            float lv[8] = {l0.x, l0.y, l0.z, l0.w, l1.x, l1.y, l1.z, l1.w};
            u16x8 pk;
            #pragma unroll
            for (int d = 0; d < 8; ++d) {
                __hip_bfloat16 t = __float2bfloat16(lv[d]);
                pk[d] = reinterpret_cast<unsigned short&>(t);
            }
            *reinterpret_cast<u16x8*>(outbase0 + m * 1024) = pk;
        }

        // ---- quantize pair 1 (single-chain, verbatim r13 order) ----
        {
            float sgn[15];
            #pragma unroll
            for (int k = 0; k < 15; ++k) {
                float z = 0.f;
                #pragma unroll
                for (int d = 0; d < 8; ++d) z += h1[d] * S[(c * 8 + d) * 15 + k];
                z = z - T[c * 15 + k];
                z = z - 1e-4f;
                sgn[k] = (z > 0.f) ? 1.f : ((z < 0.f) ? -1.f : 0.f);
            }
            float best = 0.f; int jm = 0;
            #pragma unroll
            for (int j = 0; j < 16; ++j) {
                float z2 = 0.f;
                #pragma unroll
                for (int k = 0; k < 15; ++k) z2 += sgn[k] * Hm[k * 16 + j];
                if (j == 0 || z2 > best) { best = z2; jm = j; }
            }
            const float4* lr = reinterpret_cast<const float4*>(LUT + (c * 16 + jm) * 8);
            float4 l0 = lr[0], l1 = lr[1];
            float lv[8] = {l0.x, l0.y, l0.z, l0.w, l1.x, l1.y, l1.z, l1.w};
            u16x8 pk;
            #pragma unroll
            for (int d = 0; d < 8; ++d) {
                __hip_bfloat16 t = __float2bfloat16(lv[d]);
                pk[d] = reinterpret_cast<unsigned short&>(t);
            }
            *reinterpret_cast<u16x8*>(outbase1 + m * 1024) = pk;
        }
    }
}

// ---------------- Kernel M: build dense conv matrix M[960][1024] bf16 + bias[960]
__global__ __launch_bounds__(256) void km(const float* __restrict__ w3, const float* __restrict__ b3,
                                          const float* __restrict__ w4, const float* __restrict__ b4,
                                          const float* __restrict__ w5, const float* __restrict__ b5,
                                          __hip_bfloat16* __restrict__ M, float* __restrict__ bias)
{
    int id = blockIdx.x * 256 + threadIdx.x;
    if (id >= FEAT * KDIM) return;
    int j = id >> 10, k = id & 1023;
    int l = k >> 7, f = k & 127;
    float val = 0.f, bv = 0.f;
    if (j < 384) {          // conv3: feature = nk*6 + p
        int nk = j / 6, p = j % 6, i = l - p;
        if (i >= 0 && i < 3) val = w3[(nk * 3 + i) * 128 + f];
        bv = b3[nk];
    } else if (j < 704) {   // conv4: feature = 384 + nk*5 + p
        int jj = j - 384, nk = jj / 5, p = jj % 5, i = l - p;
        if (i >= 0 && i < 4) val = w4[(nk * 4 + i) * 128 + f];
        bv = b4[nk];
    } else {                // conv5: feature = 704 + nk*4 + p
        int jj = j - 704, nk = jj / 4, p = jj % 4, i = l - p;
        if (i >= 0 && i < 5) val = w5[(nk * 5 + i) * 128 + f];
        bv = b5[nk];
    }
    M[id] = __float2bfloat16(val);
    if (k == 0) bias[j] = bv;
}

// ---------------- Kernel F: feat = relu(XQ @ M^T + bias)   [VERBATIM round-19]
// 2-phase double-buffered LDS GEMM. BM=128, BN=64, BK=64.
#define KF_NT 16            // K steps = 1024/64
#define KF_BUF 24576        // bytes per LDS buffer: A 16KB + B 8KB
__global__ __launch_bounds__(256) void kf(const char* __restrict__ XQg,
                                          const char* __restrict__ Mg,
                                          const float* __restrict__ bias,
                                          float* __restrict__ feat)
{
    __shared__ char smem[2 * KF_BUF];
    const int tid = threadIdx.x;
    const int lane = tid & 63, w = tid >> 6;
    const int wr = w >> 1, wc = w & 1;
    const int mrow = lane & 15, klane = lane >> 4;
    const int rowbase = blockIdx.y * 128;
    const int colbase = blockIdx.x * 64;

    auto stage = [&](int buf, int t) {
        #pragma unroll
        for (int i = 0; i < 6; ++i) {
            const int o = i * 4096 + tid * 16;       // linear byte offset in tile
            const char* src;
            if (i < 4) {                             // A region: 2 bgrp x 8 kc x 64 lnb x 16B
                int bgrp = o >> 13, kc = (o >> 10) & 7, lnb_p = (o >> 4) & 63;
                int lnb = lnb_p ^ kc;                // inverse bank-XOR on SOURCE
                src = XQg + ((size_t)(rowbase >> 6) + bgrp) * 131072
                          + (size_t)(t * 8 + kc) * 1024 + lnb * 16;
            } else {                                 // B region: rows 0..63 x 128B window
                int ob = o - 16384;
                int row = ob >> 7, kwin = ob & 127;
                int kb = kwin ^ ((row & 7) << 4);
                src = Mg + (size_t)(colbase + row) * 2048 + t * 128 + kb;
            }
            char* ldst = smem + buf * KF_BUF + i * 4096 + w * 1024;
            __builtin_amdgcn_global_load_lds(
                (const __attribute__((address_space(1))) void*)src,
                (__attribute__((address_space(3))) void*)ldst,
                16, 0, 0);
        }
    };

    f32x4 acc[4][2] = {};

    stage(0, 0);
    int cur = 0;
    for (int t = 0; t < KF_NT; ++t) {
        __syncthreads();                 // buf[cur] staged + prev reads done
        if (t < KF_NT - 1) stage(cur ^ 1, t + 1);

        const int abase = cur * KF_BUF;
        const int bbase = cur * KF_BUF + 16384;
        #pragma unroll
        for (int ks = 0; ks < 2; ++ks) {
            bf16x8 a[4], b[2];
            #pragma unroll
            for (int mf = 0; mf < 4; ++mf) {
                int row = wr * 64 + mf * 16 + mrow;
                int kc = ks * 4 + klane;
                a[mf] = *(const bf16x8*)(smem + abase + (row >> 6) * 8192
                                         + kc * 1024 + ((row & 63) ^ kc) * 16);
            }
            #pragma unroll
            for (int nf = 0; nf < 2; ++nf) {
                int row = wc * 32 + nf * 16 + mrow;
                int kb = ks * 64 + klane * 16;
                b[nf] = *(const bf16x8*)(smem + bbase + row * 128 + (kb ^ ((row & 7) << 4)));
            }
            #pragma unroll
            for (int mf = 0; mf < 4; ++mf)
                #pragma unroll
                for (int nf = 0; nf < 2; ++nf)
                    acc[mf][nf] = __builtin_amdgcn_mfma_f32_16x16x32_bf16(a[mf], b[nf], acc[mf][nf], 0, 0, 0);
        }
        cur ^= 1;
    }

    // epilogue: bias + relu, D layout col=lane&15, row=(lane>>4)*4+reg
    #pragma unroll
    for (int nf = 0; nf < 2; ++nf) {
        const int col = colbase + wc * 32 + nf * 16 + mrow;
        const float bc = bias[col];
        #pragma unroll
        for (int mf = 0; mf < 4; ++mf) {
            #pragma unroll
            for (int r = 0; r < 4; ++r) {
                int row = rowbase + wr * 64 + mf * 16 + klane * 4 + r;
                feat[(size_t)row * FEAT + col] = fmaxf(acc[mf][nf][r] + bc, 0.f);
            }
        }
    }
}

// ---------------- Kernel L: logits = feat @ fc2_w^T + b; log_softmax.
// Round-20: float4-vectorized loads (16B/lane sweet spot, G13). One wave per b,
// 4 passes of 256 cols (pass 3 masked to 48 lanes). Logits rounding shifts
// ~1e-6 (summation order change) — far under threshold; feat path untouched.
__global__ __launch_bounds__(256) void kl(const float* __restrict__ feat,
                                          const float* __restrict__ w2,
                                          const float* __restrict__ b2,
                                          float* __restrict__ out)
{
    const int b = blockIdx.x * 4 + (threadIdx.x >> 6);
    const int lane = threadIdx.x & 63;
    const float* fb = feat + (size_t)b * FEAT;

    float4 fr[4];
    #pragma unroll
    for (int p = 0; p < 4; ++p) {
        int col = p * 256 + lane * 4;
        if (p < 3 || lane < 48) fr[p] = *reinterpret_cast<const float4*>(fb + col);
        else { fr[p].x = 0.f; fr[p].y = 0.f; fr[p].z = 0.f; fr[p].w = 0.f; }
    }

    float lg[10];
    #pragma unroll
    for (int c = 0; c < 10; ++c) {
        float s = 0.f;
        #pragma unroll
        for (int p = 0; p < 4; ++p) {
            int col = p * 256 + lane * 4;
            if (p < 3 || lane < 48) {
                float4 wv = *reinterpret_cast<const float4*>(w2 + c * FEAT + col);
                s += fr[p].x * wv.x;
                s += fr[p].y * wv.y;
                s += fr[p].z * wv.z;
                s += fr[p].w * wv.w;
            }
        }
        #pragma unroll
        for (int off = 32; off >= 1; off >>= 1) s += __shfl_xor(s, off);
        lg[c] = s + b2[c];
    }
    float mx = lg[0];
    #pragma unroll
    for (int c = 1; c < 10; ++c) mx = fmaxf(mx, lg[c]);
    float se = 0.f;
    #pragma unroll
    for (int c = 0; c < 10; ++c) se += expf(lg[c] - mx);
    float ls = logf(se);
    #pragma unroll
    for (int c = 0; c < 10; ++c) if (lane == c) out[(size_t)b * 10 + c] = lg[c] - mx - ls;
}

extern "C" void kernel_launch(void* const* d_in, const int* in_sizes, int n_in,
                              void* d_out, int out_size, void* d_ws, size_t ws_size,
                              hipStream_t stream)
{
    const int*   x       = (const int*)d_in[0];
    const float* len_emb = (const float*)d_in[1];
    const float* ipd_emb = (const float*)d_in[2];
    const float* fc1_w   = (const float*)d_in[3];
    const float* fc1_b   = (const float*)d_in[4];
    const float* S       = (const float*)d_in[5];
    const float* Hm      = (const float*)d_in[6];
    const float* T       = (const float*)d_in[7];
    const float* LUT     = (const float*)d_in[8];
    const float* w3      = (const float*)d_in[9];
    const float* b3      = (const float*)d_in[10];
    const float* w4      = (const float*)d_in[11];
    const float* b4      = (const float*)d_in[12];
    const float* w5      = (const float*)d_in[13];
    const float* b5      = (const float*)d_in[14];
    const float* w2      = (const float*)d_in[15];
    const float* b2      = (const float*)d_in[16];

    char* ws = (char*)d_ws;
    char* XQ           = ws;                                  // 67108864 B (swizzled layout)
    __hip_bfloat16* M  = (__hip_bfloat16*)(ws + 67108864);    // 1966080 B
    float* bias        = (float*)(ws + 67108864 + 1966080);   // 3840 B  (total 69078784, proven bound)

    float* out_ls   = (float*)d_out;                 // 32768*10
    float* out_feat = (float*)d_out + NB * 10;       // 32768*960

    hipLaunchKernelGGL(kq, dim3(NB / 128, 4), dim3(256), 0, stream,
                       x, len_emb, ipd_emb, fc1_w, fc1_b, S, Hm, T, LUT, XQ);
    hipLaunchKernelGGL(km, dim3((FEAT * KDIM + 255) / 256), dim3(256), 0, stream,
                       w3, b3, w4, b4, w5, b5, M, bias);
    hipLaunchKernelGGL(kf, dim3(15, 256), dim3(256), 0, stream,
                       XQ, (const char*)M, bias, out_feat);
    hipLaunchKernelGGL(kl, dim3(NB / 4), dim3(256), 0, stream,
                       out_feat, w2, b2, out_ls);
}

// Round 21
// 293.722 us; speedup vs baseline: 1.1256x; 1.1256x over previous
//
#include <hip/hip_runtime.h>
#include <hip/hip_bf16.h>

// Problem dims
#define NB 32768
#define LL 8
#define EBD 128
#define NKK 64
#define FEAT 960
#define KDIM 1024   // LL*EBD

typedef __attribute__((ext_vector_type(8))) __bf16 bf16x8;
typedef __attribute__((ext_vector_type(4))) float f32x4;
typedef __attribute__((ext_vector_type(8))) unsigned short u16x8;

// ---------------- Kernel Q: embeddings + fc1 + hard quantize -> XQ (swizzled layout)
// [VERBATIM round-19: 2-pair fc1 + sequential quantizer, VGPR 124, 180us]
__global__ __launch_bounds__(256) void kq(const int* __restrict__ x,
    const float* __restrict__ len_emb, const float* __restrict__ ipd_emb,
    const float* __restrict__ fc1_w, const float* __restrict__ fc1_b,
    const float* __restrict__ S, const float* __restrict__ Hm,
    const float* __restrict__ T, const float* __restrict__ LUT,
    char* __restrict__ XQ)
{
    const int g = blockIdx.x;                       // 256 groups of 128 b
    const int w = threadIdx.x >> 6, lane = threadIdx.x & 63;
    const int l = blockIdx.y * 2 + (w >> 1);        // grid.y = 4 -> l in [0,8)
    const int half = w & 1;                         // which 8 chunks
    const int b0 = g * 128 + lane;
    const int p0 = b0 * 8 + l;
    const int p1 = (b0 + 64) * 8 + l;

    float e0[32], e1[32];
    {
        const float4* a0 = reinterpret_cast<const float4*>(len_emb + x[p0 * 2 + 0] * 16);
        const float4* c0 = reinterpret_cast<const float4*>(ipd_emb + x[p0 * 2 + 1] * 16);
        const float4* a1 = reinterpret_cast<const float4*>(len_emb + x[p1 * 2 + 0] * 16);
        const float4* c1 = reinterpret_cast<const float4*>(ipd_emb + x[p1 * 2 + 1] * 16);
        #pragma unroll
        for (int q = 0; q < 4; ++q) {
            float4 v = a0[q];
            e0[q * 4 + 0] = v.x; e0[q * 4 + 1] = v.y; e0[q * 4 + 2] = v.z; e0[q * 4 + 3] = v.w;
            v = c0[q];
            e0[16 + q * 4 + 0] = v.x; e0[16 + q * 4 + 1] = v.y; e0[16 + q * 4 + 2] = v.z; e0[16 + q * 4 + 3] = v.w;
            v = a1[q];
            e1[q * 4 + 0] = v.x; e1[q * 4 + 1] = v.y; e1[q * 4 + 2] = v.z; e1[q * 4 + 3] = v.w;
            v = c1[q];
            e1[16 + q * 4 + 0] = v.x; e1[16 + q * 4 + 1] = v.y; e1[16 + q * 4 + 2] = v.z; e1[16 + q * 4 + 3] = v.w;
        }
    }

    char* outbase0 = XQ + (size_t)(g * 2 + 0) * 131072 + (size_t)l * 16384 + lane * 16;
    char* outbase1 = XQ + (size_t)(g * 2 + 1) * 131072 + (size_t)l * 16384 + lane * 16;

    for (int mm = 0; mm < 8; ++mm) {
        const int m = half * 8 + mm;
        const int c = m & 3;

        float h0[8], h1[8];
        #pragma unroll
        for (int d = 0; d < 8; ++d) {
            const float* wr = fc1_w + (m * 8 + d) * 32;
            float acc0 = 0.f, acc1 = 0.f;
            #pragma unroll
            for (int j = 0; j < 32; ++j) {
                float wv = wr[j];
                acc0 += e0[j] * wv;
                acc1 += e1[j] * wv;
            }
            float bv = fc1_b[m * 8 + d];
            h0[d] = acc0 + bv;
            h1[d] = acc1 + bv;
        }

        // ---- quantize pair 0 (single-chain, verbatim r13 order) ----
        {
            float sgn[15];
            #pragma unroll
            for (int k = 0; k < 15; ++k) {
                float z = 0.f;
                #pragma unroll
                for (int d = 0; d < 8; ++d) z += h0[d] * S[(c * 8 + d) * 15 + k];
                z = z - T[c * 15 + k];
                z = z - 1e-4f;
                sgn[k] = (z > 0.f) ? 1.f : ((z < 0.f) ? -1.f : 0.f);
            }
            float best = 0.f; int jm = 0;
            #pragma unroll
            for (int j = 0; j < 16; ++j) {
                float z2 = 0.f;
                #pragma unroll
                for (int k = 0; k < 15; ++k) z2 += sgn[k] * Hm[k * 16 + j];
                if (j == 0 || z2 > best) { best = z2; jm = j; }
            }
            const float4* lr = reinterpret_cast<const float4*>(LUT + (c * 16 + jm) * 8);
            float4 l0 = lr[0], l1 = lr[1];
            float lv[8] = {l0.x, l0.y, l0.z, l0.w, l1.x, l1.y, l1.z, l1.w};
            u16x8 pk;
            #pragma unroll
            for (int d = 0; d < 8; ++d) {
                __hip_bfloat16 t = __float2bfloat16(lv[d]);
                pk[d] = reinterpret_cast<unsigned short&>(t);
            }
            *reinterpret_cast<u16x8*>(outbase0 + m * 1024) = pk;
        }

        // ---- quantize pair 1 (single-chain, verbatim r13 order) ----
        {
            float sgn[15];
            #pragma unroll
            for (int k = 0; k < 15; ++k) {
                float z = 0.f;
                #pragma unroll
                for (int d = 0; d < 8; ++d) z += h1[d] * S[(c * 8 + d) * 15 + k];
                z = z - T[c * 15 + k];
                z = z - 1e-4f;
                sgn[k] = (z > 0.f) ? 1.f : ((z < 0.f) ? -1.f : 0.f);
            }
            float best = 0.f; int jm = 0;
            #pragma unroll
            for (int j = 0; j < 16; ++j) {
                float z2 = 0.f;
                #pragma unroll
                for (int k = 0; k < 15; ++k) z2 += sgn[k] * Hm[k * 16 + j];
                if (j == 0 || z2 > best) { best = z2; jm = j; }
            }
            const float4* lr = reinterpret_cast<const float4*>(LUT + (c * 16 + jm) * 8);
            float4 l0 = lr[0], l1 = lr[1];
            float lv[8] = {l0.x, l0.y, l0.z, l0.w, l1.x, l1.y, l1.z, l1.w};
            u16x8 pk;
            #pragma unroll
            for (int d = 0; d < 8; ++d) {
                __hip_bfloat16 t = __float2bfloat16(lv[d]);
                pk[d] = reinterpret_cast<unsigned short&>(t);
            }
            *reinterpret_cast<u16x8*>(outbase1 + m * 1024) = pk;
        }
    }
}

// ---------------- Kernel M: build dense conv matrix M[960][1024] bf16 + bias[960]
__global__ __launch_bounds__(256) void km(const float* __restrict__ w3, const float* __restrict__ b3,
                                          const float* __restrict__ w4, const float* __restrict__ b4,
                                          const float* __restrict__ w5, const float* __restrict__ b5,
                                          __hip_bfloat16* __restrict__ M, float* __restrict__ bias)
{
    int id = blockIdx.x * 256 + threadIdx.x;
    if (id >= FEAT * KDIM) return;
    int j = id >> 10, k = id & 1023;
    int l = k >> 7, f = k & 127;
    float val = 0.f, bv = 0.f;
    if (j < 384) {          // conv3: feature = nk*6 + p
        int nk = j / 6, p = j % 6, i = l - p;
        if (i >= 0 && i < 3) val = w3[(nk * 3 + i) * 128 + f];
        bv = b3[nk];
    } else if (j < 704) {   // conv4: feature = 384 + nk*5 + p
        int jj = j - 384, nk = jj / 5, p = jj % 5, i = l - p;
        if (i >= 0 && i < 4) val = w4[(nk * 4 + i) * 128 + f];
        bv = b4[nk];
    } else {                // conv5: feature = 704 + nk*4 + p
        int jj = j - 704, nk = jj / 4, p = jj % 4, i = l - p;
        if (i >= 0 && i < 5) val = w5[(nk * 5 + i) * 128 + f];
        bv = b5[nk];
    }
    M[id] = __float2bfloat16(val);
    if (k == 0) bias[j] = bv;
}

// ---------------- Kernel F: feat = relu(XQ @ M^T + bias)
// Round-21: BN 64 -> 192 (960 = 5x192 exact). 2-phase double-buffered LDS GEMM,
// BM=128, BN=192, BK=64. 4 waves as 2x2: wave-tile 64x96 = acc[4][6] (24 MFMA
// per K-half-step; 3x more MFMA per barrier than r20). Col-tiles 15 -> 5:
// A-panel L3 traffic 3x down. Per-output accumulation order unchanged ->
// feat bit-identical to r20. B keeps the proven (row&7)<<4 byte-XOR.
#define KF_NT 16            // K steps = 1024/64
#define KF_BUF 40960        // bytes per LDS buffer: A 16KB + B 24KB
__global__ __launch_bounds__(256) void kf(const char* __restrict__ XQg,
                                          const char* __restrict__ Mg,
                                          const float* __restrict__ bias,
                                          float* __restrict__ feat)
{
    __shared__ char smem[2 * KF_BUF];
    const int tid = threadIdx.x;
    const int lane = tid & 63, w = tid >> 6;
    const int wr = w >> 1, wc = w & 1;
    const int mrow = lane & 15, klane = lane >> 4;
    const int rowbase = blockIdx.y * 128;
    const int colbase = blockIdx.x * 192;

    auto stage = [&](int buf, int t) {
        #pragma unroll
        for (int i = 0; i < 10; ++i) {
            const int o = i * 4096 + tid * 16;       // linear byte offset in tile
            const char* src;
            if (i < 4) {                             // A region: 2 bgrp x 8 kc x 64 lnb x 16B
                int bgrp = o >> 13, kc = (o >> 10) & 7, lnb_p = (o >> 4) & 63;
                int lnb = lnb_p ^ kc;                // inverse bank-XOR on SOURCE
                src = XQg + ((size_t)(rowbase >> 6) + bgrp) * 131072
                          + (size_t)(t * 8 + kc) * 1024 + lnb * 16;
            } else {                                 // B region: rows 0..191 x 128B window
                int ob = o - 16384;
                int row = ob >> 7, kwin = ob & 127;
                int kb = kwin ^ ((row & 7) << 4);
                src = Mg + (size_t)(colbase + row) * 2048 + t * 128 + kb;
            }
            char* ldst = smem + buf * KF_BUF + i * 4096 + w * 1024;
            __builtin_amdgcn_global_load_lds(
                (const __attribute__((address_space(1))) void*)src,
                (__attribute__((address_space(3))) void*)ldst,
                16, 0, 0);
        }
    };

    f32x4 acc[4][6] = {};

    stage(0, 0);
    int cur = 0;
    for (int t = 0; t < KF_NT; ++t) {
        __syncthreads();                 // buf[cur] staged + prev reads done
        if (t < KF_NT - 1) stage(cur ^ 1, t + 1);

        const int abase = cur * KF_BUF;
        const int bbase = cur * KF_BUF + 16384;
        #pragma unroll
        for (int ks = 0; ks < 2; ++ks) {
            bf16x8 a[4], b[6];
            #pragma unroll
            for (int mf = 0; mf < 4; ++mf) {
                int row = wr * 64 + mf * 16 + mrow;
                int kc = ks * 4 + klane;
                a[mf] = *(const bf16x8*)(smem + abase + (row >> 6) * 8192
                                         + kc * 1024 + ((row & 63) ^ kc) * 16);
            }
            #pragma unroll
            for (int nf = 0; nf < 6; ++nf) {
                int row = wc * 96 + nf * 16 + mrow;
                int kb = ks * 64 + klane * 16;
                b[nf] = *(const bf16x8*)(smem + bbase + row * 128 + (kb ^ ((row & 7) << 4)));
            }
            #pragma unroll
            for (int mf = 0; mf < 4; ++mf)
                #pragma unroll
                for (int nf = 0; nf < 6; ++nf)
                    acc[mf][nf] = __builtin_amdgcn_mfma_f32_16x16x32_bf16(a[mf], b[nf], acc[mf][nf], 0, 0, 0);
        }
        cur ^= 1;
    }

    // epilogue: bias + relu, D layout col=lane&15, row=(lane>>4)*4+reg
    #pragma unroll
    for (int nf = 0; nf < 6; ++nf) {
        const int col = colbase + wc * 96 + nf * 16 + mrow;
        const float bc = bias[col];
        #pragma unroll
        for (int mf = 0; mf < 4; ++mf) {
            #pragma unroll
            for (int r = 0; r < 4; ++r) {
                int row = rowbase + wr * 64 + mf * 16 + klane * 4 + r;
                feat[(size_t)row * FEAT + col] = fmaxf(acc[mf][nf][r] + bc, 0.f);
            }
        }
    }
}

// ---------------- Kernel L: logits = feat @ fc2_w^T + b; log_softmax.
// [VERBATIM round-20: float4 loads, one wave per b]
__global__ __launch_bounds__(256) void kl(const float* __restrict__ feat,
                                          const float* __restrict__ w2,
                                          const float* __restrict__ b2,
                                          float* __restrict__ out)
{
    const int b = blockIdx.x * 4 + (threadIdx.x >> 6);
    const int lane = threadIdx.x & 63;
    const float* fb = feat + (size_t)b * FEAT;

    float4 fr[4];
    #pragma unroll
    for (int p = 0; p < 4; ++p) {
        int col = p * 256 + lane * 4;
        if (p < 3 || lane < 48) fr[p] = *reinterpret_cast<const float4*>(fb + col);
        else { fr[p].x = 0.f; fr[p].y = 0.f; fr[p].z = 0.f; fr[p].w = 0.f; }
    }

    float lg[10];
    #pragma unroll
    for (int c = 0; c < 10; ++c) {
        float s = 0.f;
        #pragma unroll
        for (int p = 0; p < 4; ++p) {
            int col = p * 256 + lane * 4;
            if (p < 3 || lane < 48) {
                float4 wv = *reinterpret_cast<const float4*>(w2 + c * FEAT + col);
                s += fr[p].x * wv.x;
                s += fr[p].y * wv.y;
                s += fr[p].z * wv.z;
                s += fr[p].w * wv.w;
            }
        }
        #pragma unroll
        for (int off = 32; off >= 1; off >>= 1) s += __shfl_xor(s, off);
        lg[c] = s + b2[c];
    }
    float mx = lg[0];
    #pragma unroll
    for (int c = 1; c < 10; ++c) mx = fmaxf(mx, lg[c]);
    float se = 0.f;
    #pragma unroll
    for (int c = 0; c < 10; ++c) se += expf(lg[c] - mx);
    float ls = logf(se);
    #pragma unroll
    for (int c = 0; c < 10; ++c) if (lane == c) out[(size_t)b * 10 + c] = lg[c] - mx - ls;
}

extern "C" void kernel_launch(void* const* d_in, const int* in_sizes, int n_in,
                              void* d_out, int out_size, void* d_ws, size_t ws_size,
                              hipStream_t stream)
{
    const int*   x       = (const int*)d_in[0];
    const float* len_emb = (const float*)d_in[1];
    const float* ipd_emb = (const float*)d_in[2];
    const float* fc1_w   = (const float*)d_in[3];
    const float* fc1_b   = (const float*)d_in[4];
    const float* S       = (const float*)d_in[5];
    const float* Hm      = (const float*)d_in[6];
    const float* T       = (const float*)d_in[7];
    const float* LUT     = (const float*)d_in[8];
    const float* w3      = (const float*)d_in[9];
    const float* b3      = (const float*)d_in[10];
    const float* w4      = (const float*)d_in[11];
    const float* b4      = (const float*)d_in[12];
    const float* w5      = (const float*)d_in[13];
    const float* b5      = (const float*)d_in[14];
    const float* w2      = (const float*)d_in[15];
    const float* b2      = (const float*)d_in[16];

    char* ws = (char*)d_ws;
    char* XQ           = ws;                                  // 67108864 B (swizzled layout)
    __hip_bfloat16* M  = (__hip_bfloat16*)(ws + 67108864);    // 1966080 B
    float* bias        = (float*)(ws + 67108864 + 1966080);   // 3840 B  (total 69078784, proven bound)

    float* out_ls   = (float*)d_out;                 // 32768*10
    float* out_feat = (float*)d_out + NB * 10;       // 32768*960

    hipLaunchKernelGGL(kq, dim3(NB / 128, 4), dim3(256), 0, stream,
                       x, len_emb, ipd_emb, fc1_w, fc1_b, S, Hm, T, LUT, XQ);
    hipLaunchKernelGGL(km, dim3((FEAT * KDIM + 255) / 256), dim3(256), 0, stream,
                       w3, b3, w4, b4, w5, b5, M, bias);
    hipLaunchKernelGGL(kf, dim3(5, 256), dim3(256), 0, stream,
                       XQ, (const char*)M, bias, out_feat);
    hipLaunchKernelGGL(kl, dim3(NB / 4), dim3(256), 0, stream,
                       out_feat, w2, b2, out_ls);
}